// Round 15
// baseline (499.070 us; speedup 1.0000x reference)
//
#include <hip/hip_runtime.h>
#include <hip/hip_bf16.h>

#define DD 256
#define TROWS 16     // tile rows; acc[4], 8 blocks/CU (HW wave cap)
#define BSTRIDE 264  // bf16 elements per row in xt LDS tiles (528 B)
#define SBYTES (TROWS * 528)   // stage buffer: holds 16x512 staged ef OR 16x528 xt

typedef __attribute__((ext_vector_type(8))) short bf16x8;
typedef __attribute__((ext_vector_type(4))) float f32x4;

__device__ __forceinline__ unsigned cvt_pk_bf16(float lo, float hi) {
    unsigned r;
    asm("v_cvt_pk_bf16_f32 %0, %1, %2" : "=v"(r) : "v"(lo), "v"(hi));
    return r;
}

__device__ __forceinline__ ushort f2bf(float f) {
    unsigned u = __float_as_uint(f);
    u += 0x7fffu + ((u >> 16) & 1u);
    return (ushort)(u >> 16);
}
__device__ __forceinline__ float bf2f(ushort h) {
    return __uint_as_float(((unsigned)h) << 16);
}

__device__ __forceinline__ float mish_f(float t) {
    float u = __expf(t);
    float w = u * (u + 2.0f);
    float r = t * w * __builtin_amdgcn_rcpf(w + 2.0f);
    return (t > 15.0f) ? t : r;
}

// Stage 16 rows x 256 cols fp32 -> bf16 LDS, XOR-swizzled.
__device__ __forceinline__ void stage16(const float* __restrict__ src, size_t rowStride,
                                        int rowsValid, char* lds) {
    const int t = threadIdx.x;
#pragma unroll
    for (int i = 0; i < 2; ++i) {
        int c = i * 256 + t;
        int row = c >> 5;
        int col8 = (c & 31) << 3;
        float4 va = make_float4(0.f, 0.f, 0.f, 0.f);
        float4 vb = va;
        if (row < rowsValid) {
            const float* p = src + (size_t)row * rowStride + col8;
            va = *(const float4*)p;
            vb = *(const float4*)(p + 4);
        }
        uint4 h;
        h.x = cvt_pk_bf16(va.x, va.y);
        h.y = cvt_pk_bf16(va.z, va.w);
        h.z = cvt_pk_bf16(vb.x, vb.y);
        h.w = cvt_pk_bf16(vb.z, vb.w);
        int off = row * 512 + ((((c & 31) << 4)) ^ ((row & 7) << 4));
        *(uint4*)(lds + off) = h;
    }
}

// GEMM core for a 16x256 tile: 4 waves; wave w covers rows 0-15 x cols [w*64, +64).
__device__ __forceinline__ void gemm16(const char* lds, const ushort* __restrict__ Wf,
                                       f32x4 acc[4]) {
    const int lane = threadIdx.x & 63;
    const int wave = threadIdx.x >> 6;
    const int arow = lane & 15;
    const int halfk = lane >> 4;
    const int ctg0 = wave * 4;
    const bf16x8* Wfrag = (const bf16x8*)Wf;
#pragma unroll
    for (int ks = 0; ks < 8; ++ks) {
        int kbyte = ks * 64 + halfk * 16;
        bf16x8 a = *(const bf16x8*)(lds + arow * 512 + (kbyte ^ ((arow & 7) << 4)));
#pragma unroll
        for (int ct = 0; ct < 4; ++ct) {
            bf16x8 b = Wfrag[((ctg0 + ct) * 8 + ks) * 64 + lane];
            acc[ct] = __builtin_amdgcn_mfma_f32_16x16x32_bf16(a, b, acc[ct], 0, 0, 0);
        }
    }
}

__global__ void __launch_bounds__(256) convert_w_kernel(const float* __restrict__ in,
                                                        ushort* __restrict__ out, int nfrag) {
    int f = blockIdx.x * blockDim.x + threadIdx.x;
    if (f >= nfrag) return;
    int lane = f & 63;
    int ks = (f >> 6) & 7;
    int ct = f >> 9;
    int row = ct * 16 + (lane & 15);
    int kbase = ks * 32 + (lane >> 4) * 8;
    const float* p = in + (size_t)row * DD + kbase;
    float4 a = *(const float4*)p;
    float4 b = *(const float4*)(p + 4);
    ushort4 h0, h1;
    h0.x = f2bf(a.x); h0.y = f2bf(a.y); h0.z = f2bf(a.z); h0.w = f2bf(a.w);
    h1.x = f2bf(b.x); h1.y = f2bf(b.y); h1.z = f2bf(b.z); h1.w = f2bf(b.w);
    ushort4* o = (ushort4*)(out + (size_t)f * 8);
    o[0] = h0; o[1] = h1;
}

__global__ void __launch_bounds__(256) zero_kernel(int* __restrict__ p, int n) {
    int i = blockIdx.x * blockDim.x + threadIdx.x;
    if (i < n) p[i] = 0;
}

__global__ void __launch_bounds__(256) hist_kernel(const int* __restrict__ dst,
                                                   int* __restrict__ h, int E) {
    int e = blockIdx.x * blockDim.x + threadIdx.x;
    if (e < E) atomicAdd(&h[dst[e]], 1);
}

__global__ void __launch_bounds__(256) scan1_kernel(const int* __restrict__ h,
                                                    int* __restrict__ excl,
                                                    int* __restrict__ bsum, int n) {
    __shared__ int wsum[4];
    const int lane = threadIdx.x & 63;
    const int wave = threadIdx.x >> 6;
    int i = blockIdx.x * 256 + threadIdx.x;
    int v = (i < n) ? h[i] : 0;
    int s = v;
#pragma unroll
    for (int off = 1; off < 64; off <<= 1) {
        int u = __shfl_up(s, off, 64);
        if (lane >= off) s += u;
    }
    if (lane == 63) wsum[wave] = s;
    __syncthreads();
    int prefix = 0;
    for (int wv = 0; wv < wave; ++wv) prefix += wsum[wv];
    if (i < n) excl[i] = prefix + s - v;
    if (threadIdx.x == 255) bsum[blockIdx.x] = prefix + s;
}

__global__ void __launch_bounds__(256) scan2_kernel(int* __restrict__ bsum, int nb) {
    __shared__ int wsum[4];
    const int lane = threadIdx.x & 63;
    const int wave = threadIdx.x >> 6;
    int i = threadIdx.x;
    int v = (i < nb) ? bsum[i] : 0;
    int s = v;
#pragma unroll
    for (int off = 1; off < 64; off <<= 1) {
        int u = __shfl_up(s, off, 64);
        if (lane >= off) s += u;
    }
    if (lane == 63) wsum[wave] = s;
    __syncthreads();
    int prefix = 0;
    for (int wv = 0; wv < wave; ++wv) prefix += wsum[wv];
    if (i < nb) bsum[i] = prefix + s - v;
}

__global__ void __launch_bounds__(256) scan3_kernel(int* __restrict__ excl,
                                                    const int* __restrict__ bsum, int n) {
    int i = blockIdx.x * 256 + threadIdx.x;
    if (i < n) excl[i] += bsum[blockIdx.x];
}

__global__ void __launch_bounds__(256) scatter_kernel(const int* __restrict__ src,
                                                      const int* __restrict__ dst,
                                                      int* __restrict__ h2,
                                                      int* __restrict__ permS,
                                                      int* __restrict__ srcS,
                                                      int* __restrict__ dstS, int E) {
    int e = blockIdx.x * blockDim.x + threadIdx.x;
    if (e < E) {
        int d = dst[e];
        int pos = atomicAdd(&h2[d], 1);
        permS[pos] = e;
        srcS[pos] = src[e];
        dstS[pos] = d;
    }
}

// x = mish(node @ Wd^T + bd); write bf16 to xbf (ws) and f32 to agg (d_out)
__global__ void __launch_bounds__(256, 8) node_kernel(const float* __restrict__ nf,
                                                      const ushort* __restrict__ Wd,
                                                      const float* __restrict__ bd,
                                                      ushort* __restrict__ xbf,
                                                      float* __restrict__ agg, int M) {
    __shared__ char lds[TROWS * 512];
    const int base = blockIdx.x * TROWS;
    const int rowsValid = min(TROWS, M - base);
    stage16(nf + (size_t)base * DD, DD, rowsValid, lds);
    __syncthreads();
    f32x4 acc[4];
#pragma unroll
    for (int i = 0; i < 4; ++i) acc[i] = (f32x4){0.f, 0.f, 0.f, 0.f};
    gemm16(lds, Wd, acc);
    const int lane = threadIdx.x & 63;
    const int wave = threadIdx.x >> 6;
    const int colBase = wave * 64;
    const int r = lane & 15, q = lane >> 4;
#pragma unroll
    for (int ct = 0; ct < 4; ++ct) {
        int col = colBase + ct * 16 + r;
        float bb = bd[col];
#pragma unroll
        for (int j = 0; j < 4; ++j) {
            int lrow = q * 4 + j;
            if (lrow < rowsValid) {
                size_t idx = (size_t)(base + lrow) * DD + col;
                float m = mish_f(acc[ct][j] + bb);
                xbf[idx] = (ushort)cvt_pk_bf16(m, m);
                agg[idx] = m;
            }
        }
    }
}

// Persistent pipelined edge kernel (2-phase, T3-minimal):
// grid-stride over 16-row tiles; ef loads for tile k+1 issued during tile k's
// GEMM/epilogue/reduce (global->reg), converted+parked at next iteration's top.
// Stage LDS double-buffered; idx arrays triple-buffered (mod-3) so the reduce of
// tile k never races tile k+1's idx write -> 4 barriers per tile, no extra.
__global__ void __launch_bounds__(256, 8) edge_kernel(const float* __restrict__ ef,
                                                      const ushort* __restrict__ We,
                                                      const float* __restrict__ be,
                                                      const ushort* __restrict__ xbf,
                                                      const int* __restrict__ permS,
                                                      const int* __restrict__ srcS,
                                                      const int* __restrict__ dstS,
                                                      float* __restrict__ agg,
                                                      int E, int nTiles) {
    __shared__ char stage[2][SBYTES];          // 2 x 8448 B
    __shared__ int idxP[3][TROWS], idxS[3][TROWS], idxD[3][TROWS];

    const int t = threadIdx.x;
    const int G = gridDim.x;
    const int lane = t & 63;
    const int wave = t >> 6;
    const int colBase = wave * 64;
    const int r = lane & 15, q = lane >> 4;

    int tile = blockIdx.x;
    if (tile >= nTiles) return;

    // --- prologue: idx(tile0) -> LDS slot 0; issue ef(tile0); preload idx(tile1) regs
    if (t < TROWS) {
        int gi = tile * TROWS + t;
        int gic = min(gi, E - 1);
        idxP[0][t] = permS[gic];
        idxS[0][t] = srcS[gic];
        idxD[0][t] = (gi < E) ? dstS[gic] : -1;
    }
    __syncthreads();

    float4 va[2], vb[2];
    {
        int rv0 = min(TROWS, E - tile * TROWS);
#pragma unroll
        for (int i = 0; i < 2; ++i) {
            int c = i * 256 + t;
            int row = c >> 5;
            int col8 = (c & 31) << 3;
            va[i] = make_float4(0.f, 0.f, 0.f, 0.f);
            vb[i] = va[i];
            if (row < rv0) {
                const float* p = ef + (size_t)idxP[0][row] * DD + col8;
                va[i] = *(const float4*)p;
                vb[i] = *(const float4*)(p + 4);
            }
        }
    }
    int pN = 0, sN = 0, dN = -1;
    {
        int nextTile = tile + G;
        if (t < TROWS && nextTile < nTiles) {
            int gi = nextTile * TROWS + t;
            int gic = min(gi, E - 1);
            pN = permS[gic];
            sN = srcS[gic];
            dN = (gi < E) ? dstS[gic] : -1;
        }
    }

    int k = 0;
    for (; tile < nTiles; tile += G, ++k) {
        const int cur = k & 1;
        const int ic = k % 3;
        const int inx = (k + 1) % 3;
        const int nextTile = tile + G;
        const int rv = min(TROWS, E - tile * TROWS);
        const int rvN = (nextTile < nTiles) ? min(TROWS, E - nextTile * TROWS) : 0;

        // --- phase A: convert+park ef(tile) regs -> stage[cur]; park idx(next) -> LDS
#pragma unroll
        for (int i = 0; i < 2; ++i) {
            int c = i * 256 + t;
            int row = c >> 5;
            uint4 h;
            h.x = cvt_pk_bf16(va[i].x, va[i].y);
            h.y = cvt_pk_bf16(va[i].z, va[i].w);
            h.z = cvt_pk_bf16(vb[i].x, vb[i].y);
            h.w = cvt_pk_bf16(vb[i].z, vb[i].w);
            int off = row * 512 + ((((c & 31) << 4)) ^ ((row & 7) << 4));
            *(uint4*)(stage[cur] + off) = h;
        }
        if (t < TROWS && nextTile < nTiles) {
            idxP[inx][t] = pN;
            idxS[inx][t] = sN;
            idxD[inx][t] = dN;
        }
        __syncthreads();   // [1] stage + next idx visible

        // --- phase B: issue ef(next) + x(cur) loads; preload idx(next+G); GEMM
#pragma unroll
        for (int i = 0; i < 2; ++i) {
            int c = i * 256 + t;
            int row = c >> 5;
            int col8 = (c & 31) << 3;
            va[i] = make_float4(0.f, 0.f, 0.f, 0.f);
            vb[i] = va[i];
            if (row < rvN) {
                const float* p = ef + (size_t)idxP[inx][row] * DD + col8;
                va[i] = *(const float4*)p;
                vb[i] = *(const float4*)(p + 4);
            }
        }
        int4 xv[2];
#pragma unroll
        for (int i = 0; i < 2; ++i) {
            int c = i * 256 + t;
            int row = c >> 5;
            int col8 = (c & 31) << 3;
            xv[i] = make_int4(0, 0, 0, 0);
            if (row < rv)
                xv[i] = *(const int4*)(xbf + (size_t)idxS[ic][row] * DD + col8);
        }
        {
            int nnTile = tile + 2 * G;
            pN = 0; sN = 0; dN = -1;
            if (t < TROWS && nnTile < nTiles) {
                int gi = nnTile * TROWS + t;
                int gic = min(gi, E - 1);
                pN = permS[gic];
                sN = srcS[gic];
                dN = (gi < E) ? dstS[gic] : -1;
            }
        }
        f32x4 acc[4];
#pragma unroll
        for (int i = 0; i < 4; ++i) acc[i] = (f32x4){0.f, 0.f, 0.f, 0.f};
        gemm16(stage[cur], We, acc);
        __syncthreads();   // [2] stage[cur] reads done -> reusable as xt

        // --- phase C: park x into xt (= stage[cur])
        ushort* xt = (ushort*)stage[cur];
#pragma unroll
        for (int i = 0; i < 2; ++i) {
            int c = i * 256 + t;
            int row = c >> 5;
            int col8 = (c & 31) << 3;
            *(int4*)(xt + row * BSTRIDE + col8) = xv[i];
        }
        __syncthreads();   // [3] xt visible

        // --- phase D: epilogue msg = relu(x + mish(acc+be)) in place over xt
#pragma unroll
        for (int ct = 0; ct < 4; ++ct) {
            int col = colBase + ct * 16 + r;
            float bb = be[col];
#pragma unroll
            for (int j = 0; j < 4; ++j) {
                int lrow = q * 4 + j;
                float y = mish_f(acc[ct][j] + bb);
                float xval = bf2f(xt[lrow * BSTRIDE + col]);
                float msg = (lrow < rv) ? fmaxf(xval + y, 0.f) : 0.f;
                xt[lrow * BSTRIDE + col] = (ushort)cvt_pk_bf16(msg, msg);
            }
        }
        __syncthreads();   // [4] msg visible

        // --- phase E: run-reduction (col t), atomics. No trailing barrier needed:
        // next iter writes stage[cur^1] and idx[(k+2)%3], neither touched here.
        {
            int col = t;
            float run = 0.f;
            int dprev = idxD[ic][0];
#pragma unroll
            for (int r2 = 0; r2 < TROWS; ++r2) {
                int d = idxD[ic][r2];
                if (d != dprev) {
                    if (dprev >= 0) atomicAdd(agg + (size_t)dprev * DD + col, run);
                    run = 0.f;
                    dprev = d;
                }
                run += bf2f(xt[r2 * BSTRIDE + col]);
            }
            if (dprev >= 0) atomicAdd(agg + (size_t)dprev * DD + col, run);
        }
    }
}

// out = mish(agg @ Wo^T + bo), in place on agg (= d_out)
__global__ void __launch_bounds__(256, 8) out_kernel(const ushort* __restrict__ Wo,
                                                     const float* __restrict__ bo,
                                                     float* __restrict__ agg_out, int M) {
    __shared__ char lds[TROWS * 512];
    const int base = blockIdx.x * TROWS;
    const int rowsValid = min(TROWS, M - base);
    stage16(agg_out + (size_t)base * DD, DD, rowsValid, lds);
    __syncthreads();
    f32x4 acc[4];
#pragma unroll
    for (int i = 0; i < 4; ++i) acc[i] = (f32x4){0.f, 0.f, 0.f, 0.f};
    gemm16(lds, Wo, acc);
    const int lane = threadIdx.x & 63;
    const int wave = threadIdx.x >> 6;
    const int colBase = wave * 64;
    const int r = lane & 15, q = lane >> 4;
#pragma unroll
    for (int ct = 0; ct < 4; ++ct) {
        int col = colBase + ct * 16 + r;
        float bb = bo[col];
#pragma unroll
        for (int j = 0; j < 4; ++j) {
            int lrow = q * 4 + j;
            if (lrow < rowsValid) {
                size_t idx = (size_t)(base + lrow) * DD + col;
                agg_out[idx] = mish_f(acc[ct][j] + bb);
            }
        }
    }
}

extern "C" void kernel_launch(void* const* d_in, const int* in_sizes, int n_in,
                              void* d_out, int out_size, void* d_ws, size_t ws_size,
                              hipStream_t stream) {
    const float* nf = (const float*)d_in[0];
    const float* ef = (const float*)d_in[1];
    const int* src = (const int*)d_in[3];
    const int* dst = (const int*)d_in[4];
    const float* Wd = (const float*)d_in[5];
    const float* bd = (const float*)d_in[6];
    const float* We = (const float*)d_in[7];
    const float* be = (const float*)d_in[8];
    const float* Wo = (const float*)d_in[9];
    const float* bo = (const float*)d_in[10];

    const int M = in_sizes[0] / DD;   // 20000
    const int E = in_sizes[1] / DD;   // 320000
    float* out = (float*)d_out;       // agg: rst = x + sum(msg)

    auto align = [](size_t v) { return (v + 255) & ~(size_t)255; };
    char* ws = (char*)d_ws;
    size_t off = 0;
    ushort* xbf = (ushort*)(ws + off); off += align((size_t)M * DD * 2);
    ushort* Wdb = (ushort*)(ws + off); off += align((size_t)DD * DD * 2);
    ushort* Web = (ushort*)(ws + off); off += align((size_t)DD * DD * 2);
    ushort* Wob = (ushort*)(ws + off); off += align((size_t)DD * DD * 2);
    int* h     = (int*)(ws + off); off += align((size_t)M * 4);
    int* h2    = (int*)(ws + off); off += align((size_t)M * 4);
    int* bsum  = (int*)(ws + off); off += align(256 * 4);
    int* permS = (int*)(ws + off); off += align((size_t)E * 4);
    int* srcS  = (int*)(ws + off); off += align((size_t)E * 4);
    int* dstS  = (int*)(ws + off); off += align((size_t)E * 4);

    const int nfrag = (DD / 16) * (DD / 32) * 64;  // 8192 fragments per weight
    convert_w_kernel<<<(nfrag + 255) / 256, 256, 0, stream>>>(Wd, Wdb, nfrag);
    convert_w_kernel<<<(nfrag + 255) / 256, 256, 0, stream>>>(We, Web, nfrag);
    convert_w_kernel<<<(nfrag + 255) / 256, 256, 0, stream>>>(Wo, Wob, nfrag);

    // Counting sort by dst (hierarchical scan)
    const int nbScan = (M + 255) / 256;
    zero_kernel<<<(M + 255) / 256, 256, 0, stream>>>(h, M);
    hist_kernel<<<(E + 255) / 256, 256, 0, stream>>>(dst, h, E);
    scan1_kernel<<<nbScan, 256, 0, stream>>>(h, h2, bsum, M);
    scan2_kernel<<<1, 256, 0, stream>>>(bsum, nbScan);
    scan3_kernel<<<nbScan, 256, 0, stream>>>(h2, bsum, M);
    scatter_kernel<<<(E + 255) / 256, 256, 0, stream>>>(src, dst, h2, permS, srcS, dstS, E);

    const int nwgN = (M + TROWS - 1) / TROWS;   // 1250
    node_kernel<<<nwgN, 256, 0, stream>>>(nf, Wdb, bd, xbf, out, M);

    const int nTiles = (E + TROWS - 1) / TROWS; // 20000
    int gridE = 256 * 8;                        // 8 persistent blocks/CU
    if (gridE > nTiles) gridE = nTiles;
    edge_kernel<<<gridE, 256, 0, stream>>>(ef, Web, be, xbf, permS, srcS, dstS, out, E, nTiles);

    out_kernel<<<nwgN, 256, 0, stream>>>(Wob, bo, out, M);
}

// Round 16
// 453.428 us; speedup vs baseline: 1.1007x; 1.1007x over previous
//
#include <hip/hip_runtime.h>
#include <hip/hip_bf16.h>

#define DD 256
#define TROWS 16     // tile rows; acc[4]
#define BSTRIDE 264  // bf16 elements per row in xt LDS tiles (528 B)
#define SBYTES (TROWS * 528)   // stage buffer: holds 16x512 staged ef OR 16x528 xt

typedef __attribute__((ext_vector_type(8))) short bf16x8;
typedef __attribute__((ext_vector_type(4))) float f32x4;

__device__ __forceinline__ unsigned cvt_pk_bf16(float lo, float hi) {
    unsigned r;
    asm("v_cvt_pk_bf16_f32 %0, %1, %2" : "=v"(r) : "v"(lo), "v"(hi));
    return r;
}

__device__ __forceinline__ ushort f2bf(float f) {
    unsigned u = __float_as_uint(f);
    u += 0x7fffu + ((u >> 16) & 1u);
    return (ushort)(u >> 16);
}
__device__ __forceinline__ float bf2f(ushort h) {
    return __uint_as_float(((unsigned)h) << 16);
}

__device__ __forceinline__ float mish_f(float t) {
    float u = __expf(t);
    float w = u * (u + 2.0f);
    float r = t * w * __builtin_amdgcn_rcpf(w + 2.0f);
    return (t > 15.0f) ? t : r;
}

// Stage 16 rows x 256 cols fp32 -> bf16 LDS, XOR-swizzled.
__device__ __forceinline__ void stage16(const float* __restrict__ src, size_t rowStride,
                                        int rowsValid, char* lds) {
    const int t = threadIdx.x;
#pragma unroll
    for (int i = 0; i < 2; ++i) {
        int c = i * 256 + t;
        int row = c >> 5;
        int col8 = (c & 31) << 3;
        float4 va = make_float4(0.f, 0.f, 0.f, 0.f);
        float4 vb = va;
        if (row < rowsValid) {
            const float* p = src + (size_t)row * rowStride + col8;
            va = *(const float4*)p;
            vb = *(const float4*)(p + 4);
        }
        uint4 h;
        h.x = cvt_pk_bf16(va.x, va.y);
        h.y = cvt_pk_bf16(va.z, va.w);
        h.z = cvt_pk_bf16(vb.x, vb.y);
        h.w = cvt_pk_bf16(vb.z, vb.w);
        int off = row * 512 + ((((c & 31) << 4)) ^ ((row & 7) << 4));
        *(uint4*)(lds + off) = h;
    }
}

// GEMM core for a 16x256 tile: 4 waves; wave w covers rows 0-15 x cols [w*64, +64).
__device__ __forceinline__ void gemm16(const char* lds, const ushort* __restrict__ Wf,
                                       f32x4 acc[4]) {
    const int lane = threadIdx.x & 63;
    const int wave = threadIdx.x >> 6;
    const int arow = lane & 15;
    const int halfk = lane >> 4;
    const int ctg0 = wave * 4;
    const bf16x8* Wfrag = (const bf16x8*)Wf;
#pragma unroll
    for (int ks = 0; ks < 8; ++ks) {
        int kbyte = ks * 64 + halfk * 16;
        bf16x8 a = *(const bf16x8*)(lds + arow * 512 + (kbyte ^ ((arow & 7) << 4)));
#pragma unroll
        for (int ct = 0; ct < 4; ++ct) {
            bf16x8 b = Wfrag[((ctg0 + ct) * 8 + ks) * 64 + lane];
            acc[ct] = __builtin_amdgcn_mfma_f32_16x16x32_bf16(a, b, acc[ct], 0, 0, 0);
        }
    }
}

__global__ void __launch_bounds__(256) convert_w_kernel(const float* __restrict__ in,
                                                        ushort* __restrict__ out, int nfrag) {
    int f = blockIdx.x * blockDim.x + threadIdx.x;
    if (f >= nfrag) return;
    int lane = f & 63;
    int ks = (f >> 6) & 7;
    int ct = f >> 9;
    int row = ct * 16 + (lane & 15);
    int kbase = ks * 32 + (lane >> 4) * 8;
    const float* p = in + (size_t)row * DD + kbase;
    float4 a = *(const float4*)p;
    float4 b = *(const float4*)(p + 4);
    ushort4 h0, h1;
    h0.x = f2bf(a.x); h0.y = f2bf(a.y); h0.z = f2bf(a.z); h0.w = f2bf(a.w);
    h1.x = f2bf(b.x); h1.y = f2bf(b.y); h1.z = f2bf(b.z); h1.w = f2bf(b.w);
    ushort4* o = (ushort4*)(out + (size_t)f * 8);
    o[0] = h0; o[1] = h1;
}

__global__ void __launch_bounds__(256) zero_kernel(int* __restrict__ p, int n) {
    int i = blockIdx.x * blockDim.x + threadIdx.x;
    if (i < n) p[i] = 0;
}

__global__ void __launch_bounds__(256) hist_kernel(const int* __restrict__ dst,
                                                   int* __restrict__ h, int E) {
    int e = blockIdx.x * blockDim.x + threadIdx.x;
    if (e < E) atomicAdd(&h[dst[e]], 1);
}

__global__ void __launch_bounds__(256) scan1_kernel(const int* __restrict__ h,
                                                    int* __restrict__ excl,
                                                    int* __restrict__ bsum, int n) {
    __shared__ int wsum[4];
    const int lane = threadIdx.x & 63;
    const int wave = threadIdx.x >> 6;
    int i = blockIdx.x * 256 + threadIdx.x;
    int v = (i < n) ? h[i] : 0;
    int s = v;
#pragma unroll
    for (int off = 1; off < 64; off <<= 1) {
        int u = __shfl_up(s, off, 64);
        if (lane >= off) s += u;
    }
    if (lane == 63) wsum[wave] = s;
    __syncthreads();
    int prefix = 0;
    for (int wv = 0; wv < wave; ++wv) prefix += wsum[wv];
    if (i < n) excl[i] = prefix + s - v;
    if (threadIdx.x == 255) bsum[blockIdx.x] = prefix + s;
}

__global__ void __launch_bounds__(256) scan2_kernel(int* __restrict__ bsum, int nb) {
    __shared__ int wsum[4];
    const int lane = threadIdx.x & 63;
    const int wave = threadIdx.x >> 6;
    int i = threadIdx.x;
    int v = (i < nb) ? bsum[i] : 0;
    int s = v;
#pragma unroll
    for (int off = 1; off < 64; off <<= 1) {
        int u = __shfl_up(s, off, 64);
        if (lane >= off) s += u;
    }
    if (lane == 63) wsum[wave] = s;
    __syncthreads();
    int prefix = 0;
    for (int wv = 0; wv < wave; ++wv) prefix += wsum[wv];
    if (i < nb) bsum[i] = prefix + s - v;
}

__global__ void __launch_bounds__(256) scan3_kernel(int* __restrict__ excl,
                                                    const int* __restrict__ bsum, int n) {
    int i = blockIdx.x * 256 + threadIdx.x;
    if (i < n) excl[i] += bsum[blockIdx.x];
}

__global__ void __launch_bounds__(256) scatter_kernel(const int* __restrict__ src,
                                                      const int* __restrict__ dst,
                                                      int* __restrict__ h2,
                                                      int* __restrict__ permS,
                                                      int* __restrict__ srcS,
                                                      int* __restrict__ dstS, int E) {
    int e = blockIdx.x * blockDim.x + threadIdx.x;
    if (e < E) {
        int d = dst[e];
        int pos = atomicAdd(&h2[d], 1);
        permS[pos] = e;
        srcS[pos] = src[e];
        dstS[pos] = d;
    }
}

// x = mish(node @ Wd^T + bd); write bf16 to xbf (ws) and f32 to agg (d_out)
__global__ void __launch_bounds__(256, 8) node_kernel(const float* __restrict__ nf,
                                                      const ushort* __restrict__ Wd,
                                                      const float* __restrict__ bd,
                                                      ushort* __restrict__ xbf,
                                                      float* __restrict__ agg, int M) {
    __shared__ char lds[TROWS * 512];
    const int base = blockIdx.x * TROWS;
    const int rowsValid = min(TROWS, M - base);
    stage16(nf + (size_t)base * DD, DD, rowsValid, lds);
    __syncthreads();
    f32x4 acc[4];
#pragma unroll
    for (int i = 0; i < 4; ++i) acc[i] = (f32x4){0.f, 0.f, 0.f, 0.f};
    gemm16(lds, Wd, acc);
    const int lane = threadIdx.x & 63;
    const int wave = threadIdx.x >> 6;
    const int colBase = wave * 64;
    const int r = lane & 15, q = lane >> 4;
#pragma unroll
    for (int ct = 0; ct < 4; ++ct) {
        int col = colBase + ct * 16 + r;
        float bb = bd[col];
#pragma unroll
        for (int j = 0; j < 4; ++j) {
            int lrow = q * 4 + j;
            if (lrow < rowsValid) {
                size_t idx = (size_t)(base + lrow) * DD + col;
                float m = mish_f(acc[ct][j] + bb);
                xbf[idx] = (ushort)cvt_pk_bf16(m, m);
                agg[idx] = m;
            }
        }
    }
}

// Persistent pipelined edge kernel (2-phase, T3-minimal). Identical logic to r15
// (refcheck'd); launch_bounds (256,6): budget ~85 regs >= ~60 needed (r14 body 32
// + 24 pipeline in-flight + loop state) -> no spill at 6 blocks/CU (r15 spilled at cap-8).
__global__ void __launch_bounds__(256, 6) edge_kernel(const float* __restrict__ ef,
                                                      const ushort* __restrict__ We,
                                                      const float* __restrict__ be,
                                                      const ushort* __restrict__ xbf,
                                                      const int* __restrict__ permS,
                                                      const int* __restrict__ srcS,
                                                      const int* __restrict__ dstS,
                                                      float* __restrict__ agg,
                                                      int E, int nTiles) {
    __shared__ char stage[2][SBYTES];          // 2 x 8448 B
    __shared__ int idxP[3][TROWS], idxS[3][TROWS], idxD[3][TROWS];

    const int t = threadIdx.x;
    const int G = gridDim.x;
    const int lane = t & 63;
    const int wave = t >> 6;
    const int colBase = wave * 64;
    const int r = lane & 15, q = lane >> 4;

    int tile = blockIdx.x;
    if (tile >= nTiles) return;

    // --- prologue: idx(tile0) -> LDS slot 0; issue ef(tile0); preload idx(tile1) regs
    if (t < TROWS) {
        int gi = tile * TROWS + t;
        int gic = min(gi, E - 1);
        idxP[0][t] = permS[gic];
        idxS[0][t] = srcS[gic];
        idxD[0][t] = (gi < E) ? dstS[gic] : -1;
    }
    __syncthreads();

    float4 va[2], vb[2];
    {
        int rv0 = min(TROWS, E - tile * TROWS);
#pragma unroll
        for (int i = 0; i < 2; ++i) {
            int c = i * 256 + t;
            int row = c >> 5;
            int col8 = (c & 31) << 3;
            va[i] = make_float4(0.f, 0.f, 0.f, 0.f);
            vb[i] = va[i];
            if (row < rv0) {
                const float* p = ef + (size_t)idxP[0][row] * DD + col8;
                va[i] = *(const float4*)p;
                vb[i] = *(const float4*)(p + 4);
            }
        }
    }
    int pN = 0, sN = 0, dN = -1;
    {
        int nextTile = tile + G;
        if (t < TROWS && nextTile < nTiles) {
            int gi = nextTile * TROWS + t;
            int gic = min(gi, E - 1);
            pN = permS[gic];
            sN = srcS[gic];
            dN = (gi < E) ? dstS[gic] : -1;
        }
    }

    int k = 0;
    for (; tile < nTiles; tile += G, ++k) {
        const int cur = k & 1;
        const int ic = k % 3;
        const int inx = (k + 1) % 3;
        const int nextTile = tile + G;
        const int rv = min(TROWS, E - tile * TROWS);
        const int rvN = (nextTile < nTiles) ? min(TROWS, E - nextTile * TROWS) : 0;

        // --- phase A: convert+park ef(tile) regs -> stage[cur]; park idx(next) -> LDS
#pragma unroll
        for (int i = 0; i < 2; ++i) {
            int c = i * 256 + t;
            int row = c >> 5;
            uint4 h;
            h.x = cvt_pk_bf16(va[i].x, va[i].y);
            h.y = cvt_pk_bf16(va[i].z, va[i].w);
            h.z = cvt_pk_bf16(vb[i].x, vb[i].y);
            h.w = cvt_pk_bf16(vb[i].z, vb[i].w);
            int off = row * 512 + ((((c & 31) << 4)) ^ ((row & 7) << 4));
            *(uint4*)(stage[cur] + off) = h;
        }
        if (t < TROWS && nextTile < nTiles) {
            idxP[inx][t] = pN;
            idxS[inx][t] = sN;
            idxD[inx][t] = dN;
        }
        __syncthreads();   // [1] stage + next idx visible

        // --- phase B: issue ef(next) + x(cur) loads; preload idx(next+G); GEMM
#pragma unroll
        for (int i = 0; i < 2; ++i) {
            int c = i * 256 + t;
            int row = c >> 5;
            int col8 = (c & 31) << 3;
            va[i] = make_float4(0.f, 0.f, 0.f, 0.f);
            vb[i] = va[i];
            if (row < rvN) {
                const float* p = ef + (size_t)idxP[inx][row] * DD + col8;
                va[i] = *(const float4*)p;
                vb[i] = *(const float4*)(p + 4);
            }
        }
        int4 xv[2];
#pragma unroll
        for (int i = 0; i < 2; ++i) {
            int c = i * 256 + t;
            int row = c >> 5;
            int col8 = (c & 31) << 3;
            xv[i] = make_int4(0, 0, 0, 0);
            if (row < rv)
                xv[i] = *(const int4*)(xbf + (size_t)idxS[ic][row] * DD + col8);
        }
        {
            int nnTile = tile + 2 * G;
            pN = 0; sN = 0; dN = -1;
            if (t < TROWS && nnTile < nTiles) {
                int gi = nnTile * TROWS + t;
                int gic = min(gi, E - 1);
                pN = permS[gic];
                sN = srcS[gic];
                dN = (gi < E) ? dstS[gic] : -1;
            }
        }
        f32x4 acc[4];
#pragma unroll
        for (int i = 0; i < 4; ++i) acc[i] = (f32x4){0.f, 0.f, 0.f, 0.f};
        gemm16(stage[cur], We, acc);
        __syncthreads();   // [2] stage[cur] reads done -> reusable as xt

        // --- phase C: park x into xt (= stage[cur])
        ushort* xt = (ushort*)stage[cur];
#pragma unroll
        for (int i = 0; i < 2; ++i) {
            int c = i * 256 + t;
            int row = c >> 5;
            int col8 = (c & 31) << 3;
            *(int4*)(xt + row * BSTRIDE + col8) = xv[i];
        }
        __syncthreads();   // [3] xt visible

        // --- phase D: epilogue msg = relu(x + mish(acc+be)) in place over xt
#pragma unroll
        for (int ct = 0; ct < 4; ++ct) {
            int col = colBase + ct * 16 + r;
            float bb = be[col];
#pragma unroll
            for (int j = 0; j < 4; ++j) {
                int lrow = q * 4 + j;
                float y = mish_f(acc[ct][j] + bb);
                float xval = bf2f(xt[lrow * BSTRIDE + col]);
                float msg = (lrow < rv) ? fmaxf(xval + y, 0.f) : 0.f;
                xt[lrow * BSTRIDE + col] = (ushort)cvt_pk_bf16(msg, msg);
            }
        }
        __syncthreads();   // [4] msg visible

        // --- phase E: run-reduction (col t), atomics. No trailing barrier needed:
        // next iter writes stage[cur^1] and idx[(k+2)%3], neither touched here.
        {
            int col = t;
            float run = 0.f;
            int dprev = idxD[ic][0];
#pragma unroll
            for (int r2 = 0; r2 < TROWS; ++r2) {
                int d = idxD[ic][r2];
                if (d != dprev) {
                    if (dprev >= 0) atomicAdd(agg + (size_t)dprev * DD + col, run);
                    run = 0.f;
                    dprev = d;
                }
                run += bf2f(xt[r2 * BSTRIDE + col]);
            }
            if (dprev >= 0) atomicAdd(agg + (size_t)dprev * DD + col, run);
        }
    }
}

// out = mish(agg @ Wo^T + bo), in place on agg (= d_out)
__global__ void __launch_bounds__(256, 8) out_kernel(const ushort* __restrict__ Wo,
                                                     const float* __restrict__ bo,
                                                     float* __restrict__ agg_out, int M) {
    __shared__ char lds[TROWS * 512];
    const int base = blockIdx.x * TROWS;
    const int rowsValid = min(TROWS, M - base);
    stage16(agg_out + (size_t)base * DD, DD, rowsValid, lds);
    __syncthreads();
    f32x4 acc[4];
#pragma unroll
    for (int i = 0; i < 4; ++i) acc[i] = (f32x4){0.f, 0.f, 0.f, 0.f};
    gemm16(lds, Wo, acc);
    const int lane = threadIdx.x & 63;
    const int wave = threadIdx.x >> 6;
    const int colBase = wave * 64;
    const int r = lane & 15, q = lane >> 4;
#pragma unroll
    for (int ct = 0; ct < 4; ++ct) {
        int col = colBase + ct * 16 + r;
        float bb = bo[col];
#pragma unroll
        for (int j = 0; j < 4; ++j) {
            int lrow = q * 4 + j;
            if (lrow < rowsValid) {
                size_t idx = (size_t)(base + lrow) * DD + col;
                agg_out[idx] = mish_f(acc[ct][j] + bb);
            }
        }
    }
}

extern "C" void kernel_launch(void* const* d_in, const int* in_sizes, int n_in,
                              void* d_out, int out_size, void* d_ws, size_t ws_size,
                              hipStream_t stream) {
    const float* nf = (const float*)d_in[0];
    const float* ef = (const float*)d_in[1];
    const int* src = (const int*)d_in[3];
    const int* dst = (const int*)d_in[4];
    const float* Wd = (const float*)d_in[5];
    const float* bd = (const float*)d_in[6];
    const float* We = (const float*)d_in[7];
    const float* be = (const float*)d_in[8];
    const float* Wo = (const float*)d_in[9];
    const float* bo = (const float*)d_in[10];

    const int M = in_sizes[0] / DD;   // 20000
    const int E = in_sizes[1] / DD;   // 320000
    float* out = (float*)d_out;       // agg: rst = x + sum(msg)

    auto align = [](size_t v) { return (v + 255) & ~(size_t)255; };
    char* ws = (char*)d_ws;
    size_t off = 0;
    ushort* xbf = (ushort*)(ws + off); off += align((size_t)M * DD * 2);
    ushort* Wdb = (ushort*)(ws + off); off += align((size_t)DD * DD * 2);
    ushort* Web = (ushort*)(ws + off); off += align((size_t)DD * DD * 2);
    ushort* Wob = (ushort*)(ws + off); off += align((size_t)DD * DD * 2);
    int* h     = (int*)(ws + off); off += align((size_t)M * 4);
    int* h2    = (int*)(ws + off); off += align((size_t)M * 4);
    int* bsum  = (int*)(ws + off); off += align(256 * 4);
    int* permS = (int*)(ws + off); off += align((size_t)E * 4);
    int* srcS  = (int*)(ws + off); off += align((size_t)E * 4);
    int* dstS  = (int*)(ws + off); off += align((size_t)E * 4);

    const int nfrag = (DD / 16) * (DD / 32) * 64;  // 8192 fragments per weight
    convert_w_kernel<<<(nfrag + 255) / 256, 256, 0, stream>>>(Wd, Wdb, nfrag);
    convert_w_kernel<<<(nfrag + 255) / 256, 256, 0, stream>>>(We, Web, nfrag);
    convert_w_kernel<<<(nfrag + 255) / 256, 256, 0, stream>>>(Wo, Wob, nfrag);

    // Counting sort by dst (hierarchical scan)
    const int nbScan = (M + 255) / 256;
    zero_kernel<<<(M + 255) / 256, 256, 0, stream>>>(h, M);
    hist_kernel<<<(E + 255) / 256, 256, 0, stream>>>(dst, h, E);
    scan1_kernel<<<nbScan, 256, 0, stream>>>(h, h2, bsum, M);
    scan2_kernel<<<1, 256, 0, stream>>>(bsum, nbScan);
    scan3_kernel<<<nbScan, 256, 0, stream>>>(h2, bsum, M);
    scatter_kernel<<<(E + 255) / 256, 256, 0, stream>>>(src, dst, h2, permS, srcS, dstS, E);

    const int nwgN = (M + TROWS - 1) / TROWS;   // 1250
    node_kernel<<<nwgN, 256, 0, stream>>>(nf, Wdb, bd, xbf, out, M);

    const int nTiles = (E + TROWS - 1) / TROWS; // 20000
    int gridE = 256 * 6;                        // 6 persistent blocks/CU (reg budget 85)
    if (gridE > nTiles) gridE = nTiles;
    edge_kernel<<<gridE, 256, 0, stream>>>(ef, Web, be, xbf, permS, srcS, dstS, out, E, nTiles);

    out_kernel<<<nwgN, 256, 0, stream>>>(Wob, bo, out, M);
}

// Round 17
// 270.821 us; speedup vs baseline: 1.8428x; 1.6743x over previous
//
#include <hip/hip_runtime.h>
#include <hip/hip_bf16.h>

#define DD 256
#define TROWS 16     // tile rows; acc[4] -> ~32 VGPR, 8 blocks/CU (HW wave cap)
#define BSTRIDE 264  // bf16 elements per row in LDS tiles (528 B, 16B-aligned)

typedef __attribute__((ext_vector_type(8))) short bf16x8;
typedef __attribute__((ext_vector_type(4))) float f32x4;

// v_cvt_pk_bf16_f32: D[15:0]=bf16(lo), D[31:16]=bf16(hi), RNE. No builtin on gfx950 (m240).
__device__ __forceinline__ unsigned cvt_pk_bf16(float lo, float hi) {
    unsigned r;
    asm("v_cvt_pk_bf16_f32 %0, %1, %2" : "=v"(r) : "v"(lo), "v"(hi));
    return r;
}

__device__ __forceinline__ ushort f2bf(float f) {   // scalar fallback (repack kernel)
    unsigned u = __float_as_uint(f);
    u += 0x7fffu + ((u >> 16) & 1u);
    return (ushort)(u >> 16);
}
__device__ __forceinline__ float bf2f(ushort h) {
    return __uint_as_float(((unsigned)h) << 16);
}

__device__ __forceinline__ float mish_f(float t) {
    float u = __expf(t);
    float w = u * (u + 2.0f);
    float r = t * w * __builtin_amdgcn_rcpf(w + 2.0f);
    return (t > 15.0f) ? t : r;
}

// Stage 16 rows x 256 cols fp32 -> bf16 LDS, XOR-swizzled (row*512 + (kbyte ^ ((row&7)<<4))).
__device__ __forceinline__ void stage16(const float* __restrict__ src, size_t rowStride,
                                        int rowsValid, char* lds) {
    const int t = threadIdx.x;
#pragma unroll
    for (int i = 0; i < 2; ++i) {
        int c = i * 256 + t;           // 16B-dest chunk id, 0..511
        int row = c >> 5;              // 32 chunks per row
        int col8 = (c & 31) << 3;      // 8-float group
        float4 va = make_float4(0.f, 0.f, 0.f, 0.f);
        float4 vb = va;
        if (row < rowsValid) {
            const float* p = src + (size_t)row * rowStride + col8;
            va = *(const float4*)p;
            vb = *(const float4*)(p + 4);
        }
        uint4 h;
        h.x = cvt_pk_bf16(va.x, va.y);
        h.y = cvt_pk_bf16(va.z, va.w);
        h.z = cvt_pk_bf16(vb.x, vb.y);
        h.w = cvt_pk_bf16(vb.z, vb.w);
        int off = row * 512 + ((((c & 31) << 4)) ^ ((row & 7) << 4));
        *(uint4*)(lds + off) = h;
    }
}

// GEMM core for a 16x256 tile: 4 waves; wave w covers rows 0-15 x cols [w*64, +64).
__device__ __forceinline__ void gemm16(const char* lds, const ushort* __restrict__ Wf,
                                       f32x4 acc[4]) {
    const int lane = threadIdx.x & 63;
    const int wave = threadIdx.x >> 6;
    const int arow = lane & 15;
    const int halfk = lane >> 4;
    const int ctg0 = wave * 4;
    const bf16x8* Wfrag = (const bf16x8*)Wf;
#pragma unroll
    for (int ks = 0; ks < 8; ++ks) {
        int kbyte = ks * 64 + halfk * 16;
        bf16x8 a = *(const bf16x8*)(lds + arow * 512 + (kbyte ^ ((arow & 7) << 4)));
#pragma unroll
        for (int ct = 0; ct < 4; ++ct) {
            bf16x8 b = Wfrag[((ctg0 + ct) * 8 + ks) * 64 + lane];
            acc[ct] = __builtin_amdgcn_mfma_f32_16x16x32_bf16(a, b, acc[ct], 0, 0, 0);
        }
    }
}

// Repack W into fragment-major bf16.
__global__ void __launch_bounds__(256) convert_w_kernel(const float* __restrict__ in,
                                                        ushort* __restrict__ out, int nfrag) {
    int f = blockIdx.x * blockDim.x + threadIdx.x;
    if (f >= nfrag) return;
    int lane = f & 63;
    int ks = (f >> 6) & 7;
    int ct = f >> 9;
    int row = ct * 16 + (lane & 15);
    int kbase = ks * 32 + (lane >> 4) * 8;
    const float* p = in + (size_t)row * DD + kbase;
    float4 a = *(const float4*)p;
    float4 b = *(const float4*)(p + 4);
    ushort4 h0, h1;
    h0.x = f2bf(a.x); h0.y = f2bf(a.y); h0.z = f2bf(a.z); h0.w = f2bf(a.w);
    h1.x = f2bf(b.x); h1.y = f2bf(b.y); h1.z = f2bf(b.z); h1.w = f2bf(b.w);
    ushort4* o = (ushort4*)(out + (size_t)f * 8);
    o[0] = h0; o[1] = h1;
}

__global__ void __launch_bounds__(256) zero_kernel(int* __restrict__ p, int n) {
    int i = blockIdx.x * blockDim.x + threadIdx.x;
    if (i < n) p[i] = 0;
}

__global__ void __launch_bounds__(256) hist_kernel(const int* __restrict__ dst,
                                                   int* __restrict__ h, int E) {
    int e = blockIdx.x * blockDim.x + threadIdx.x;
    if (e < E) atomicAdd(&h[dst[e]], 1);
}

__global__ void __launch_bounds__(256) scan1_kernel(const int* __restrict__ h,
                                                    int* __restrict__ excl,
                                                    int* __restrict__ bsum, int n) {
    __shared__ int wsum[4];
    const int lane = threadIdx.x & 63;
    const int wave = threadIdx.x >> 6;
    int i = blockIdx.x * 256 + threadIdx.x;
    int v = (i < n) ? h[i] : 0;
    int s = v;
#pragma unroll
    for (int off = 1; off < 64; off <<= 1) {
        int u = __shfl_up(s, off, 64);
        if (lane >= off) s += u;
    }
    if (lane == 63) wsum[wave] = s;
    __syncthreads();
    int prefix = 0;
    for (int wv = 0; wv < wave; ++wv) prefix += wsum[wv];
    if (i < n) excl[i] = prefix + s - v;
    if (threadIdx.x == 255) bsum[blockIdx.x] = prefix + s;
}

__global__ void __launch_bounds__(256) scan2_kernel(int* __restrict__ bsum, int nb) {
    __shared__ int wsum[4];
    const int lane = threadIdx.x & 63;
    const int wave = threadIdx.x >> 6;
    int i = threadIdx.x;
    int v = (i < nb) ? bsum[i] : 0;
    int s = v;
#pragma unroll
    for (int off = 1; off < 64; off <<= 1) {
        int u = __shfl_up(s, off, 64);
        if (lane >= off) s += u;
    }
    if (lane == 63) wsum[wave] = s;
    __syncthreads();
    int prefix = 0;
    for (int wv = 0; wv < wave; ++wv) prefix += wsum[wv];
    if (i < nb) bsum[i] = prefix + s - v;
}

__global__ void __launch_bounds__(256) scan3_kernel(int* __restrict__ excl,
                                                    const int* __restrict__ bsum, int n) {
    int i = blockIdx.x * 256 + threadIdx.x;
    if (i < n) excl[i] += bsum[blockIdx.x];
}

__global__ void __launch_bounds__(256) scatter_kernel(const int* __restrict__ src,
                                                      const int* __restrict__ dst,
                                                      int* __restrict__ h2,
                                                      int* __restrict__ permS,
                                                      int* __restrict__ srcS,
                                                      int* __restrict__ dstS, int E) {
    int e = blockIdx.x * blockDim.x + threadIdx.x;
    if (e < E) {
        int d = dst[e];
        int pos = atomicAdd(&h2[d], 1);
        permS[pos] = e;
        srcS[pos] = src[e];
        dstS[pos] = d;
    }
}

// x = mish(node @ Wd^T + bd); write bf16 to xbf (ws) and f32 to agg (d_out)
__global__ void __launch_bounds__(256, 8) node_kernel(const float* __restrict__ nf,
                                                      const ushort* __restrict__ Wd,
                                                      const float* __restrict__ bd,
                                                      ushort* __restrict__ xbf,
                                                      float* __restrict__ agg, int M) {
    __shared__ char lds[TROWS * 512];
    const int base = blockIdx.x * TROWS;
    const int rowsValid = min(TROWS, M - base);
    stage16(nf + (size_t)base * DD, DD, rowsValid, lds);
    __syncthreads();
    f32x4 acc[4];
#pragma unroll
    for (int i = 0; i < 4; ++i) acc[i] = (f32x4){0.f, 0.f, 0.f, 0.f};
    gemm16(lds, Wd, acc);
    const int lane = threadIdx.x & 63;
    const int wave = threadIdx.x >> 6;
    const int colBase = wave * 64;
    const int r = lane & 15, q = lane >> 4;
#pragma unroll
    for (int ct = 0; ct < 4; ++ct) {
        int col = colBase + ct * 16 + r;
        float bb = bd[col];
#pragma unroll
        for (int j = 0; j < 4; ++j) {
            int lrow = q * 4 + j;
            if (lrow < rowsValid) {
                size_t idx = (size_t)(base + lrow) * DD + col;
                float m = mish_f(acc[ct][j] + bb);
                xbf[idx] = (ushort)cvt_pk_bf16(m, m);
                agg[idx] = m;
            }
        }
    }
}

// Sorted-edge kernel, 16-row tile. T14 split: x[src] gather loads ISSUED before the
// GEMM barrier (latency hides under MFMA + Wfrag streaming), parked to LDS after.
// VGPR ~32 under the 64-reg (256,8) budget -> 8 blocks/CU spill-free (r14 verified).
__global__ void __launch_bounds__(256, 8) edge_kernel(const float* __restrict__ ef,
                                                      const ushort* __restrict__ We,
                                                      const float* __restrict__ be,
                                                      const ushort* __restrict__ xbf,
                                                      const int* __restrict__ permS,
                                                      const int* __restrict__ srcS,
                                                      const int* __restrict__ dstS,
                                                      float* __restrict__ agg, int E) {
    __shared__ char smem[TROWS * BSTRIDE * 2];  // 8448 B: staging (16*512 swz) / xt (16*528)
    __shared__ int permRow[TROWS];
    __shared__ int srcRow[TROWS];
    __shared__ int dstRow[TROWS];

    const int t = threadIdx.x;
    const int base = blockIdx.x * TROWS;
    const int rowsValid = min(TROWS, E - base);

    if (t < TROWS) {
        int gi = base + t;
        int gic = (gi < E) ? gi : (E - 1);
        permRow[t] = permS[gic];
        srcRow[t] = srcS[gic];
        dstRow[t] = (gi < E) ? dstS[gic] : -1;
    }
    __syncthreads();

    // Stage ef rows (16 x 256 fp32 -> bf16 swizzled): 2 iters, cvt_pk + 16B ds_writes.
#pragma unroll
    for (int i = 0; i < 2; ++i) {
        int c = i * 256 + t;
        int row = c >> 5;
        int col8 = (c & 31) << 3;
        float4 va = make_float4(0.f, 0.f, 0.f, 0.f);
        float4 vb = va;
        if (row < rowsValid) {
            const float* p = ef + (size_t)permRow[row] * DD + col8;
            va = *(const float4*)p;
            vb = *(const float4*)(p + 4);
        }
        uint4 h;
        h.x = cvt_pk_bf16(va.x, va.y);
        h.y = cvt_pk_bf16(va.z, va.w);
        h.z = cvt_pk_bf16(vb.x, vb.y);
        h.w = cvt_pk_bf16(vb.z, vb.w);
        int off = row * 512 + ((((c & 31) << 4)) ^ ((row & 7) << 4));
        *(uint4*)(smem + off) = h;
    }

    // T14 issue-early: x[src] gather loads issued BEFORE the GEMM; parked after.
    int4 xv[2];
    int xrow[2], xcol8[2];
#pragma unroll
    for (int i = 0; i < 2; ++i) {
        int c = i * 256 + t;
        xrow[i] = c >> 5;
        xcol8[i] = (c & 31) << 3;
        xv[i] = make_int4(0, 0, 0, 0);
        if (xrow[i] < rowsValid)
            xv[i] = *(const int4*)(xbf + (size_t)srcRow[xrow[i]] * DD + xcol8[i]);
    }
    __syncthreads();   // staging visible

    f32x4 acc[4];
#pragma unroll
    for (int i = 0; i < 4; ++i) acc[i] = (f32x4){0.f, 0.f, 0.f, 0.f};
    gemm16(smem, We, acc);
    __syncthreads();   // staged ef consumed; smem reusable

    // Write-late: park prefetched x rows into LDS.
    ushort* xt = (ushort*)smem;   // [16][BSTRIDE]
#pragma unroll
    for (int i = 0; i < 2; ++i)
        *(int4*)(xt + xrow[i] * BSTRIDE + xcol8[i]) = xv[i];
    __syncthreads();

    // Epilogue: y = mish(acc + be); msg = relu(x + y) written in place over xt.
    const int lane = t & 63;
    const int wave = t >> 6;
    const int colBase = wave * 64;
    const int r = lane & 15, q = lane >> 4;
#pragma unroll
    for (int ct = 0; ct < 4; ++ct) {
        int col = colBase + ct * 16 + r;
        float bb = be[col];
#pragma unroll
        for (int j = 0; j < 4; ++j) {
            int lrow = q * 4 + j;
            float y = mish_f(acc[ct][j] + bb);
            float xval = bf2f(xt[lrow * BSTRIDE + col]);
            float msg = (lrow < rowsValid) ? fmaxf(xval + y, 0.f) : 0.f;
            xt[lrow * BSTRIDE + col] = (ushort)cvt_pk_bf16(msg, msg);
        }
    }
    __syncthreads();

    // Run-reduction: thread t owns col t; dst broadcast -> uniform branches.
    {
        int col = t;
        float run = 0.f;
        int dprev = dstRow[0];
#pragma unroll
        for (int r2 = 0; r2 < TROWS; ++r2) {
            int d = dstRow[r2];
            if (d != dprev) {
                if (dprev >= 0) atomicAdd(agg + (size_t)dprev * DD + col, run);
                run = 0.f;
                dprev = d;
            }
            run += bf2f(xt[r2 * BSTRIDE + col]);
        }
        if (dprev >= 0) atomicAdd(agg + (size_t)dprev * DD + col, run);
    }
}

// out = mish(agg @ Wo^T + bo), in place on agg (= d_out)
__global__ void __launch_bounds__(256, 8) out_kernel(const ushort* __restrict__ Wo,
                                                     const float* __restrict__ bo,
                                                     float* __restrict__ agg_out, int M) {
    __shared__ char lds[TROWS * 512];
    const int base = blockIdx.x * TROWS;
    const int rowsValid = min(TROWS, M - base);
    stage16(agg_out + (size_t)base * DD, DD, rowsValid, lds);
    __syncthreads();
    f32x4 acc[4];
#pragma unroll
    for (int i = 0; i < 4; ++i) acc[i] = (f32x4){0.f, 0.f, 0.f, 0.f};
    gemm16(lds, Wo, acc);
    const int lane = threadIdx.x & 63;
    const int wave = threadIdx.x >> 6;
    const int colBase = wave * 64;
    const int r = lane & 15, q = lane >> 4;
#pragma unroll
    for (int ct = 0; ct < 4; ++ct) {
        int col = colBase + ct * 16 + r;
        float bb = bo[col];
#pragma unroll
        for (int j = 0; j < 4; ++j) {
            int lrow = q * 4 + j;
            if (lrow < rowsValid) {
                size_t idx = (size_t)(base + lrow) * DD + col;
                agg_out[idx] = mish_f(acc[ct][j] + bb);
            }
        }
    }
}

extern "C" void kernel_launch(void* const* d_in, const int* in_sizes, int n_in,
                              void* d_out, int out_size, void* d_ws, size_t ws_size,
                              hipStream_t stream) {
    const float* nf = (const float*)d_in[0];
    const float* ef = (const float*)d_in[1];
    const int* src = (const int*)d_in[3];
    const int* dst = (const int*)d_in[4];
    const float* Wd = (const float*)d_in[5];
    const float* bd = (const float*)d_in[6];
    const float* We = (const float*)d_in[7];
    const float* be = (const float*)d_in[8];
    const float* Wo = (const float*)d_in[9];
    const float* bo = (const float*)d_in[10];

    const int M = in_sizes[0] / DD;   // 20000
    const int E = in_sizes[1] / DD;   // 320000
    float* out = (float*)d_out;       // agg: rst = x + sum(msg)

    auto align = [](size_t v) { return (v + 255) & ~(size_t)255; };
    char* ws = (char*)d_ws;
    size_t off = 0;
    ushort* xbf = (ushort*)(ws + off); off += align((size_t)M * DD * 2);
    ushort* Wdb = (ushort*)(ws + off); off += align((size_t)DD * DD * 2);
    ushort* Web = (ushort*)(ws + off); off += align((size_t)DD * DD * 2);
    ushort* Wob = (ushort*)(ws + off); off += align((size_t)DD * DD * 2);
    int* h     = (int*)(ws + off); off += align((size_t)M * 4);
    int* h2    = (int*)(ws + off); off += align((size_t)M * 4);
    int* bsum  = (int*)(ws + off); off += align(256 * 4);
    int* permS = (int*)(ws + off); off += align((size_t)E * 4);
    int* srcS  = (int*)(ws + off); off += align((size_t)E * 4);
    int* dstS  = (int*)(ws + off); off += align((size_t)E * 4);

    const int nfrag = (DD / 16) * (DD / 32) * 64;  // 8192 fragments per weight
    convert_w_kernel<<<(nfrag + 255) / 256, 256, 0, stream>>>(Wd, Wdb, nfrag);
    convert_w_kernel<<<(nfrag + 255) / 256, 256, 0, stream>>>(We, Web, nfrag);
    convert_w_kernel<<<(nfrag + 255) / 256, 256, 0, stream>>>(Wo, Wob, nfrag);

    // Counting sort by dst (hierarchical scan)
    const int nbScan = (M + 255) / 256;
    zero_kernel<<<(M + 255) / 256, 256, 0, stream>>>(h, M);
    hist_kernel<<<(E + 255) / 256, 256, 0, stream>>>(dst, h, E);
    scan1_kernel<<<nbScan, 256, 0, stream>>>(h, h2, bsum, M);
    scan2_kernel<<<1, 256, 0, stream>>>(bsum, nbScan);
    scan3_kernel<<<nbScan, 256, 0, stream>>>(h2, bsum, M);
    scatter_kernel<<<(E + 255) / 256, 256, 0, stream>>>(src, dst, h2, permS, srcS, dstS, E);

    const int nwgN = (M + TROWS - 1) / TROWS;   // 1250
    node_kernel<<<nwgN, 256, 0, stream>>>(nf, Wdb, bd, xbf, out, M);
    const int nwgE = (E + TROWS - 1) / TROWS;   // 20000
    edge_kernel<<<nwgE, 256, 0, stream>>>(ef, Web, be, xbf, permS, srcS, dstS, out, E);
    out_kernel<<<nwgN, 256, 0, stream>>>(Wob, bo, out, M);
}